// Round 6
// baseline (114.414 us; speedup 1.0000x reference)
//
#include <hip/hip_runtime.h>
#include <hip/hip_fp16.h>

typedef __attribute__((ext_vector_type(2))) float v2f;

#define B_   16
#define NPTS 4096            // points per batch (N == M == 4096)

constexpr int BLK    = 256;          // 4 waves per block
constexpr int WV     = 4;
constexpr int PPT    = 16;           // queries per thread (8 packed pairs)
constexpr int NP     = PPT / 2;      // 8 packs
constexpr int QCHUNK = 64 * PPT;     // 1024 queries per block (shared by waves)
constexpr int NQC    = NPTS / QCHUNK;// 4 query chunks
constexpr int JT     = 512;          // targets staged per block
constexpr int NJT    = NPTS / JT;    // 8 target tiles
constexpr int SEG    = JT / WV;      // 128 targets per wave
constexpr int NRB    = 128;          // reduce blocks

// ---- forced packed fp32 fma with op_sel scalar broadcast --------------
// t = a.lo * p + c.hi   (a.lo, c.hi broadcast to both halves)
__device__ __forceinline__ v2f pk_fma_alo_chi(v2f a, v2f p, v2f c) {
    v2f t;
    asm("v_pk_fma_f32 %0, %1, %2, %3 op_sel:[0,0,1] op_sel_hi:[0,1,1]"
        : "=v"(t) : "v"(a), "v"(p), "v"(c));
    return t;
}
// t += a.hi * p
__device__ __forceinline__ void pk_fma_ahi(v2f a, v2f p, v2f& t) {
    asm("v_pk_fma_f32 %0, %1, %2, %0 op_sel:[1,0,0] op_sel_hi:[1,1,1]"
        : "+v"(t) : "v"(a), "v"(p));
}
// t += a.lo * p
__device__ __forceinline__ void pk_fma_alo(v2f a, v2f p, v2f& t) {
    asm("v_pk_fma_f32 %0, %1, %2, %0 op_sel:[0,0,0] op_sel_hi:[0,1,1]"
        : "+v"(t) : "v"(a), "v"(p));
}

// ------------------------------------------------------------------
// block = (dir, b, query-chunk of 1024, target-tile of 512).
// 4 waves share the chunk's queries (16/thread, packed pairs) and split
// the 512 staged targets 4-ways; per-wave mins (with |q|^2 folded,
// clamped) meet in LDS; block writes 1024 half partials for its tile.
__global__ __launch_bounds__(BLK, 4) void chamfer_pass(
        const float* __restrict__ pred, const float* __restrict__ gt,
        __half* __restrict__ partial) {
    const int cx  = blockIdx.x & (NQC - 1);
    const int jt  = blockIdx.x >> 2;
    const int b   = blockIdx.y;
    const int dir = blockIdx.z;

    const float* qsrc = dir ? gt   : pred;   // queries
    const float* tsrc = dir ? pred : gt;     // targets

    __shared__ float4 sh[JT];                //  8 KB prescaled targets
    __shared__ float  comb[WV][QCHUNK];      // 16 KB cross-wave combine

    const int lane = threadIdx.x & 63;
    const int wv   = threadIdx.x >> 6;

    // stage JT targets as {-2x,-2y,-2z,|g|^2}
    const float* tp = tsrc + (b * NPTS + jt * JT) * 3;
    for (int k = threadIdx.x; k < JT; k += BLK) {
        float x = tp[3 * k + 0], y = tp[3 * k + 1], z = tp[3 * k + 2];
        sh[k] = make_float4(-2.f * x, -2.f * y, -2.f * z,
                            fmaf(x, x, fmaf(y, y, z * z)));
    }

    // load this lane's 16 queries as 8 packed pairs
    v2f px[NP], py[NP], pz[NP], mn[NP];
    const float* qp = qsrc + (b * NPTS + cx * QCHUNK) * 3;
#pragma unroll
    for (int p = 0; p < NP; p++) {
        int i0 = (lane + (2 * p) * 64) * 3;
        int i1 = i0 + 64 * 3;
        px[p] = v2f{qp[i0 + 0], qp[i1 + 0]};
        py[p] = v2f{qp[i0 + 1], qp[i1 + 1]};
        pz[p] = v2f{qp[i0 + 2], qp[i1 + 2]};
        mn[p] = v2f{1e30f, 1e30f};
    }
    __syncthreads();

    // sweep this wave's 128-target segment (uniform-addr broadcast reads)
    const float4* seg = &sh[wv * SEG];
#pragma unroll 4
    for (int j = 0; j < SEG; j += 2) {
        float4 g0 = seg[j], g1 = seg[j + 1];
        v2f g0xy = {g0.x, g0.y}, g0zw = {g0.z, g0.w};
        v2f g1xy = {g1.x, g1.y}, g1zw = {g1.z, g1.w};
#pragma unroll
        for (int p = 0; p < NP; p++) {
            v2f t0 = pk_fma_alo_chi(g0xy, px[p], g0zw);  // -2x*qx + g^2
            pk_fma_ahi(g0xy, py[p], t0);                  // += -2y*qy
            pk_fma_alo(g0zw, pz[p], t0);                  // += -2z*qz
            v2f t1 = pk_fma_alo_chi(g1xy, px[p], g1zw);
            pk_fma_ahi(g1xy, py[p], t1);
            pk_fma_alo(g1zw, pz[p], t1);
            mn[p].x = fminf(mn[p].x, fminf(t0.x, t1.x));  // -> v_min3_f32
            mn[p].y = fminf(mn[p].y, fminf(t0.y, t1.y));
        }
    }

    // fold |q|^2, clamp, publish per-wave mins
#pragma unroll
    for (int p = 0; p < NP; p++) {
        v2f x2 = px[p] * px[p] + py[p] * py[p] + pz[p] * pz[p];
        comb[wv][lane + (2 * p) * 64]     = fmaxf(mn[p].x + x2.x, 0.f);
        comb[wv][lane + (2 * p + 1) * 64] = fmaxf(mn[p].y + x2.y, 0.f);
    }
    __syncthreads();

    // cross-wave min -> half partial for this (tile, query-chunk)
    __half* po = partial + (((dir * B_ + b) * NJT + jt) * NPTS) + cx * QCHUNK;
#pragma unroll
    for (int k = 0; k < QCHUNK / BLK; k++) {
        int q = k * BLK + threadIdx.x;
        float v = fminf(fminf(comb[0][q], comb[1][q]),
                        fminf(comb[2][q], comb[3][q]));
        po[q] = __float2half(v);
    }
}

// ------------------------------------------------------------------
// reduce: 128 blocks x 1024 threads, one query each. Min over NJT tile
// partials, sqrt, block-sum, atomicAdd to accum; last block (ticket)
// reads accum coherently and writes the 3 outputs.
__global__ __launch_bounds__(1024) void reduce_kernel(
        const __half* __restrict__ partial, float* __restrict__ accum,
        unsigned* __restrict__ counter, float* __restrict__ out) {
    const int slot = blockIdx.x >> 2;              // (dir*16+b) in [0,32)
    const int seg  = blockIdx.x & 3;
    const int q    = seg * 1024 + threadIdx.x;     // query within batch
    const __half* p = partial + slot * (NJT * NPTS) + q;
    float v = __half2float(p[0]);
#pragma unroll
    for (int jt = 1; jt < NJT; jt++)
        v = fminf(v, __half2float(p[jt * NPTS]));
    float s = sqrtf(v);
    for (int off = 32; off; off >>= 1) s += __shfl_down(s, off);

    __shared__ float ps[16];
    __shared__ unsigned last;
    const int lane = threadIdx.x & 63, wv = threadIdx.x >> 6;
    if (lane == 0) ps[wv] = s;
    __syncthreads();
    if (threadIdx.x == 0) {
        float t = 0.f;
#pragma unroll
        for (int w = 0; w < 16; w++) t += ps[w];
        atomicAdd(accum, t);
        __threadfence();
        last = (atomicAdd(counter, 1u) == NRB - 1) ? 1u : 0u;
        if (last) {
            float tot  = atomicAdd(accum, 0.0f);   // coherent read
            float loss = tot * (1.0f / (float)(B_ * NPTS));
            out[0] = loss;          // WEIGHT * loss, WEIGHT = 1
            out[1] = loss;          // helper_loss
            out[2] = 0.1f * loss;   // helper_cderr
        }
    }
}

// ------------------------------------------------------------------
extern "C" void kernel_launch(void* const* d_in, const int* in_sizes, int n_in,
                              void* d_out, int out_size, void* d_ws, size_t ws_size,
                              hipStream_t stream) {
    const float* pred = (const float*)d_in[0];
    const float* gt   = (const float*)d_in[1];
    float* out = (float*)d_out;

    const size_t PARTIAL_BYTES = (size_t)2 * B_ * NJT * NPTS * sizeof(__half); // 2 MB
    __half*   partial = (__half*)d_ws;
    float*    accum   = (float*)((char*)d_ws + PARTIAL_BYTES);
    unsigned* counter = (unsigned*)(accum + 1);

    hipMemsetAsync((char*)d_ws + PARTIAL_BYTES, 0, 8, stream);
    chamfer_pass<<<dim3(NQC * NJT, B_, 2), BLK, 0, stream>>>(pred, gt, partial);
    reduce_kernel<<<dim3(NRB), 1024, 0, stream>>>(partial, accum, counter, out);
}

// Round 7
// 93.227 us; speedup vs baseline: 1.2273x; 1.2273x over previous
//
#include <hip/hip_runtime.h>
#include <hip/hip_fp16.h>

typedef __attribute__((ext_vector_type(8)))  _Float16 half8;
typedef __attribute__((ext_vector_type(16))) float    f32x16;

#define B_   16
#define NPTS 4096                      // points per batch (N == M == 4096)

constexpr int BLK  = 256;              // 4 waves
constexpr int WV   = 4;
constexpr int QPW  = 32;               // queries per wave (one MFMA N-dim)
constexpr int QPB  = WV * QPW;         // 128 queries per block
constexpr int NQC  = NPTS / QPB;       // 32 query chunks
constexpr int RT   = 2048;             // targets staged per round (32 KB LDS)
constexpr int NR   = NPTS / RT;        // 2 rounds
constexpr int TPR  = RT / 32;          // 64 tiles of 32 targets per round
constexpr int NBLK = 2 * B_ * NQC;     // 1024 blocks

// ------------------------------------------------------------------
// Fused MFMA chamfer. Block = (dir, b, 128-query chunk); each wave owns
// 32 queries as a fixed B-fragment [x,y,z,1,1,0,0,0] (fp16, both K-halves
// identical). Targets staged in LDS as per-target 16B A-fragment rows
// [-2x,-2y,-2z,g2hi,g2lo,0,0,0] (|g|^2 split hi+lo for exactness). One
// mfma_f32_32x32x16_f16 per 32x32 tile gives D = 2(|g|^2 - 2 q.g); min
// over rows folds 16 accs -> running register min. d^2 = 0.5*minD + |q|^2
// (q from the SAME fp16-rounded coords -> exact perturbed-point metric).
__global__ __launch_bounds__(BLK, 4) void chamfer_mfma(
        const float* __restrict__ pred, const float* __restrict__ gt,
        float* __restrict__ accum, unsigned* __restrict__ counter,
        float* __restrict__ out) {
    const int qc  = blockIdx.x;
    const int b   = blockIdx.y;
    const int dir = blockIdx.z;
    const float* qsrc = dir ? gt   : pred;   // queries
    const float* tsrc = dir ? pred : gt;     // targets

    __shared__ uint4 sh[RT];                 // 32 KB staged A-frag rows
    __shared__ float ps[WV];

    const int tid  = threadIdx.x;
    const int lane = tid & 63;
    const int wv   = tid >> 6;
    const int m    = lane & 31;

    // ---- B fragment: this lane's query (col = lane&31 of its wave) ----
    const float* qp = qsrc + (b * NPTS + qc * QPB + wv * QPW + m) * 3;
    __half hqx = __float2half(qp[0]);
    __half hqy = __float2half(qp[1]);
    __half hqz = __float2half(qp[2]);
    float fqx = __half2float(hqx), fqy = __half2float(hqy), fqz = __half2float(hqz);
    const float q2 = fmaf(fqx, fqx, fmaf(fqy, fqy, fqz * fqz));
    uint4 bu;
    bu.x = (unsigned)__half_as_ushort(hqx) | ((unsigned)__half_as_ushort(hqy) << 16);
    bu.y = (unsigned)__half_as_ushort(hqz) | (0x3C00u << 16);   // {z, 1.0}
    bu.z = 0x3C00u;                                             // {1.0, 0}
    bu.w = 0u;
    const half8 bfrag = __builtin_bit_cast(half8, bu);

    f32x16 zero;
#pragma unroll
    for (int i = 0; i < 16; ++i) zero[i] = 0.0f;

    float mn = 1e30f;

    for (int r = 0; r < NR; ++r) {
        if (r) __syncthreads();
        // ---- stage RT targets as A-frag rows ----
        const float* tp = tsrc + (b * NPTS + r * RT) * 3;
        for (int k = 0; k < RT / BLK; ++k) {
            int j = k * BLK + tid;
            __half hx = __float2half(tp[3 * j + 0]);
            __half hy = __float2half(tp[3 * j + 1]);
            __half hz = __float2half(tp[3 * j + 2]);
            float fx = __half2float(hx), fy = __half2float(hy), fz = __half2float(hz);
            float g2 = fmaf(fx, fx, fmaf(fy, fy, fz * fz));
            __half ax = __float2half(-2.0f * fx);
            __half ay = __float2half(-2.0f * fy);
            __half az = __float2half(-2.0f * fz);
            __half g2hi = __float2half(g2);
            __half g2lo = __float2half(g2 - __half2float(g2hi));
            uint4 w;
            w.x = (unsigned)__half_as_ushort(ax) | ((unsigned)__half_as_ushort(ay) << 16);
            w.y = (unsigned)__half_as_ushort(az) | ((unsigned)__half_as_ushort(g2hi) << 16);
            w.z = (unsigned)__half_as_ushort(g2lo);
            w.w = 0u;
            sh[j] = w;
        }
        __syncthreads();

        // ---- sweep 64 tiles of 32 targets ----
#pragma unroll 2
        for (int t = 0; t < TPR; ++t) {
            uint4 au = sh[t * 32 + m];          // lanes L and L+32 share addr (free 2-way)
            half8 afrag = __builtin_bit_cast(half8, au);
            f32x16 d = __builtin_amdgcn_mfma_f32_32x32x16_f16(afrag, bfrag, zero, 0, 0, 0);
            // min over the 16 rows this lane covers (tree, depth 4)
            float a0 = fminf(d[0], d[1]),  a1 = fminf(d[2], d[3]);
            float a2 = fminf(d[4], d[5]),  a3 = fminf(d[6], d[7]);
            float a4 = fminf(d[8], d[9]),  a5 = fminf(d[10], d[11]);
            float a6 = fminf(d[12], d[13]), a7 = fminf(d[14], d[15]);
            a0 = fminf(a0, a1); a2 = fminf(a2, a3);
            a4 = fminf(a4, a5); a6 = fminf(a6, a7);
            a0 = fminf(a0, a2); a4 = fminf(a4, a6);
            mn = fminf(mn, fminf(a0, a4));
        }
    }

    // rows split across lane halves: full 32-row min needs lane ^ 32
    float v  = fminf(mn, __shfl_xor(mn, 32));
    float dd = fmaxf(fmaf(0.5f, v, q2), 0.0f);   // undo K-duplication, fold |q|^2
    float s  = sqrtf(dd);
    // butterfly sum over 64 lanes (each query counted twice -> 0.5x)
#pragma unroll
    for (int off = 32; off; off >>= 1) s += __shfl_xor(s, off);
    if (lane == 0) ps[wv] = 0.5f * s;
    __syncthreads();

    if (tid == 0) {
        float bs = ps[0] + ps[1] + ps[2] + ps[3];
        atomicAdd(accum, bs);
        __threadfence();
        if (atomicAdd(counter, 1u) == NBLK - 1) {   // last block finalizes
            float total = atomicAdd(accum, 0.0f);   // coherent read
            float loss  = total * (1.0f / (float)(B_ * NPTS));
            out[0] = loss;          // WEIGHT * loss, WEIGHT = 1
            out[1] = loss;          // helper_loss
            out[2] = 0.1f * loss;   // helper_cderr = p1 chamfer * xyz_unit
        }
    }
}

// ------------------------------------------------------------------
extern "C" void kernel_launch(void* const* d_in, const int* in_sizes, int n_in,
                              void* d_out, int out_size, void* d_ws, size_t ws_size,
                              hipStream_t stream) {
    const float* pred = (const float*)d_in[0];
    const float* gt   = (const float*)d_in[1];
    float*    out     = (float*)d_out;
    float*    accum   = (float*)d_ws;
    unsigned* counter = (unsigned*)d_ws + 1;

    hipMemsetAsync(d_ws, 0, 8, stream);
    chamfer_mfma<<<dim3(NQC, B_, 2), BLK, 0, stream>>>(pred, gt, accum, counter, out);
}

// Round 8
// 90.402 us; speedup vs baseline: 1.2656x; 1.0313x over previous
//
#include <hip/hip_runtime.h>
#include <hip/hip_fp16.h>

typedef __attribute__((ext_vector_type(8)))  _Float16 half8;
typedef __attribute__((ext_vector_type(16))) float    f32x16;

#define B_   16
#define NPTS 4096                      // points per batch (N == M == 4096)

constexpr int BLK  = 256;              // 4 waves
constexpr int WV   = 4;
constexpr int QPW  = 32;               // queries per wave (one MFMA N-dim)
constexpr int QPB  = WV * QPW;         // 128 queries per block
constexpr int NQC  = NPTS / QPB;       // 32 query chunks
constexpr int RT   = 1024;             // targets staged per round (16 KB LDS)
constexpr int NR   = NPTS / RT;        // 4 rounds
constexpr int TPR  = RT / 32;          // 32 tiles of 32 targets per round
constexpr int NBLK = 2 * B_ * NQC;     // 1024 blocks

__device__ __forceinline__ float min3f(float a, float b, float c) {
    return fminf(fminf(a, b), c);      // -> v_min3_f32
}

// ------------------------------------------------------------------
// Fused MFMA chamfer (R7 structure, tuned). Block = (dir, b, 128-query
// chunk); each wave owns 32 queries as a fixed fp16 B-fragment
// [x,y,z,1,1,0,0,0] (both K-halves identical). Targets staged in LDS as
// 16B A-fragment rows [-2x,-2y,-2z,g2hi,g2lo,0,0,0] (|g|^2 split hi+lo).
// One mfma_f32_32x32x16_f16 per 32x32 tile -> D = 2(|g|^2 - 2 q.g);
// min3-tree folds 16 accs (8 insts, depth 3). d^2 = 0.5*minD + |q|^2
// with q from the SAME fp16-rounded coords (exact perturbed metric).
__global__ __launch_bounds__(BLK, 4) void chamfer_mfma(
        const float* __restrict__ pred, const float* __restrict__ gt,
        float* __restrict__ accum, unsigned* __restrict__ counter,
        float* __restrict__ out) {
    const int qc  = blockIdx.x;
    const int b   = blockIdx.y;
    const int dir = blockIdx.z;
    const float* qsrc = dir ? gt   : pred;   // queries
    const float* tsrc = dir ? pred : gt;     // targets

    __shared__ uint4 sh[RT];                 // 16 KB staged A-frag rows
    __shared__ float ps[WV];

    const int tid  = threadIdx.x;
    const int lane = tid & 63;
    const int wv   = tid >> 6;
    const int m    = lane & 31;

    // ---- B fragment: this lane's query (col = lane&31 of its wave) ----
    const float* qp = qsrc + (b * NPTS + qc * QPB + wv * QPW + m) * 3;
    __half hqx = __float2half(qp[0]);
    __half hqy = __float2half(qp[1]);
    __half hqz = __float2half(qp[2]);
    float fqx = __half2float(hqx), fqy = __half2float(hqy), fqz = __half2float(hqz);
    const float q2 = fmaf(fqx, fqx, fmaf(fqy, fqy, fqz * fqz));
    uint4 bu;
    bu.x = (unsigned)__half_as_ushort(hqx) | ((unsigned)__half_as_ushort(hqy) << 16);
    bu.y = (unsigned)__half_as_ushort(hqz) | (0x3C00u << 16);   // {z, 1.0}
    bu.z = 0x3C00u;                                             // {1.0, 0}
    bu.w = 0u;
    const half8 bfrag = __builtin_bit_cast(half8, bu);

    f32x16 zero;
#pragma unroll
    for (int i = 0; i < 16; ++i) zero[i] = 0.0f;

    float mn = 1e30f;

    for (int r = 0; r < NR; ++r) {
        if (r) __syncthreads();
        // ---- stage RT targets as A-frag rows ----
        const float* tp = tsrc + (b * NPTS + r * RT) * 3;
#pragma unroll
        for (int k = 0; k < RT / BLK; ++k) {
            int j = k * BLK + tid;
            __half hx = __float2half(tp[3 * j + 0]);
            __half hy = __float2half(tp[3 * j + 1]);
            __half hz = __float2half(tp[3 * j + 2]);
            float fx = __half2float(hx), fy = __half2float(hy), fz = __half2float(hz);
            float g2 = fmaf(fx, fx, fmaf(fy, fy, fz * fz));
            __half ax = __float2half(-2.0f * fx);
            __half ay = __float2half(-2.0f * fy);
            __half az = __float2half(-2.0f * fz);
            __half g2hi = __float2half(g2);
            __half g2lo = __float2half(g2 - __half2float(g2hi));
            uint4 w;
            w.x = (unsigned)__half_as_ushort(ax) | ((unsigned)__half_as_ushort(ay) << 16);
            w.y = (unsigned)__half_as_ushort(az) | ((unsigned)__half_as_ushort(g2hi) << 16);
            w.z = (unsigned)__half_as_ushort(g2lo);
            w.w = 0u;
            sh[j] = w;
        }
        __syncthreads();

        // ---- sweep 32 tiles; unroll 8 -> immediate-offset ds_reads,
        //      8 loads in flight, fine-grained lgkmcnt ----
#pragma unroll 8
        for (int t = 0; t < TPR; ++t) {
            uint4 au = sh[t * 32 + m];       // lanes L and L+32 share addr (free 2-way)
            half8 afrag = __builtin_bit_cast(half8, au);
            f32x16 d = __builtin_amdgcn_mfma_f32_32x32x16_f16(afrag, bfrag, zero, 0, 0, 0);
            // min over this lane's 16 rows: 8x v_min3_f32, depth 3
            float m0 = min3f(d[0],  d[1],  d[2]);
            float m1 = min3f(d[3],  d[4],  d[5]);
            float m2 = min3f(d[6],  d[7],  d[8]);
            float m3 = min3f(d[9],  d[10], d[11]);
            float m4 = min3f(d[12], d[13], d[14]);
            float n0 = min3f(m0, m1, m2);
            float n1 = min3f(m3, m4, d[15]);
            mn = min3f(mn, n0, n1);
        }
    }

    // rows split across lane halves: full 32-row min needs lane ^ 32
    float v  = fminf(mn, __shfl_xor(mn, 32));
    float dd = fmaxf(fmaf(0.5f, v, q2), 0.0f);   // undo K-duplication, fold |q|^2
    float s  = sqrtf(dd);
    // butterfly sum over 64 lanes (each query counted twice -> 0.5x)
#pragma unroll
    for (int off = 32; off; off >>= 1) s += __shfl_xor(s, off);
    if (lane == 0) ps[wv] = 0.5f * s;
    __syncthreads();

    if (tid == 0) {
        float bs = ps[0] + ps[1] + ps[2] + ps[3];
        atomicAdd(accum, bs);
        __threadfence();
        if (atomicAdd(counter, 1u) == NBLK - 1) {   // last block finalizes
            float total = atomicAdd(accum, 0.0f);   // coherent read
            float loss  = total * (1.0f / (float)(B_ * NPTS));
            out[0] = loss;          // WEIGHT * loss, WEIGHT = 1
            out[1] = loss;          // helper_loss
            out[2] = 0.1f * loss;   // helper_cderr = p1 chamfer * xyz_unit
        }
    }
}

// ------------------------------------------------------------------
extern "C" void kernel_launch(void* const* d_in, const int* in_sizes, int n_in,
                              void* d_out, int out_size, void* d_ws, size_t ws_size,
                              hipStream_t stream) {
    const float* pred = (const float*)d_in[0];
    const float* gt   = (const float*)d_in[1];
    float*    out     = (float*)d_out;
    float*    accum   = (float*)d_ws;
    unsigned* counter = (unsigned*)d_ws + 1;

    hipMemsetAsync(d_ws, 0, 8, stream);
    chamfer_mfma<<<dim3(NQC, B_, 2), BLK, 0, stream>>>(pred, gt, accum, counter, out);
}